// Round 14
// baseline (547.049 us; speedup 1.0000x reference)
//
#include <hip/hip_runtime.h>

#define N_NODES 50000
#define N_EDGES 800000
#define N_GRAPHS 2048
#define IN_DIM 128
#define HID 256
#define N_LAYERS 4
#define BN_EPS 1e-5f
#define NBIN 128
#define WSCALE 64.0f

#define EDGE_BLKS 3125   // ceil(800000/256)
#define NODE_BLKS 196    // ceil(50000/256)

typedef unsigned short ushort_t;
typedef float f32x4 __attribute__((ext_vector_type(4)));
typedef unsigned int u32x4 __attribute__((ext_vector_type(4)));
typedef _Float16 f16x8 __attribute__((ext_vector_type(8)));
typedef _Float16 f16x4 __attribute__((ext_vector_type(4)));

// ---------------- deg count (+edge rank) + graph bounds + prep (fused grid) ----------
// R12: the deg atomic's return value IS each edge's rank within its dst group —
// store it (erank) so k_fill needs no cursor atomic at all (chain depth 3 -> 2).
__global__ __launch_bounds__(256) void k_degboundsprep(const int* __restrict__ dst,
                                                       int* __restrict__ degi,
                                                       int* __restrict__ erank,
                                                       const int* __restrict__ batch,
                                                       int* __restrict__ gstart,
                                                       int* __restrict__ gend,
                                                       const float* __restrict__ gamma,
                                                       const float* __restrict__ beta,
                                                       const float* __restrict__ mean,
                                                       const float* __restrict__ var,
                                                       const float* __restrict__ bias,
                                                       const float* __restrict__ W0,
                                                       const float* __restrict__ Ws,
                                                       const float* __restrict__ x,
                                                       float* __restrict__ scale,
                                                       float* __restrict__ shift,
                                                       _Float16* __restrict__ Wh,
                                                       _Float16* __restrict__ X16) {
    int bid = blockIdx.x;
    if (bid < EDGE_BLKS) {
        int e = bid * 256 + threadIdx.x;
        if (e < N_EDGES) erank[e] = atomicAdd(&degi[dst[e]], 1);
        return;
    }
    if (bid < EDGE_BLKS + NODE_BLKS) {
        int n = (bid - EDGE_BLKS) * 256 + threadIdx.x;
        if (n >= N_NODES) return;
        int g = batch[n];
        if (n == 0 || batch[n - 1] != g) gstart[g] = n;
        if (n == N_NODES - 1 || batch[n + 1] != g) gend[g] = n + 1;
        return;
    }
    int id = (bid - EDGE_BLKS - NODE_BLKS) * 256 + threadIdx.x;
    if (id < N_LAYERS * HID) {
        float s = gamma[id] * rsqrtf(var[id] + BN_EPS);
        scale[id] = s / WSCALE;
        shift[id] = beta[id] + (bias[id] - mean[id]) * s;
        return;
    }
    id -= N_LAYERS * HID;
    const int WT = 128 * 256 + 3 * 256 * 256;
    if (id < WT) {
        float v;
        if (id < 32768) {
            int n = id >> 7, k = id & 127;
            v = W0[k * 256 + n];
        } else {
            int t = id - 32768;
            int l = t >> 16;
            int r = t & 65535;
            int n = r >> 8, k = r & 255;
            v = Ws[l * 65536 + k * 256 + n];
        }
        Wh[id] = (_Float16)(v * WSCALE);
        return;
    }
    id -= WT;
    const int total4 = N_NODES * IN_DIM / 4;
    if (id < total4) {
        float4 v = ((const float4*)x)[id];
        int n = id >> 5;
        int c0 = (id & 31) * 4;
        f16x4 o;
        o.x = (_Float16)v.x; o.y = (_Float16)v.y; o.z = (_Float16)v.z; o.w = (_Float16)v.w;
        *(f16x4*)(X16 + (size_t)(c0 >> 5) * (N_NODES * 32) + (size_t)n * 32 + (c0 & 31)) = o;
    }
}

// ---------------- node norms + degree histogram (fused, hierarchical) ----------------
__global__ __launch_bounds__(256) void k_nodeprep(const int* __restrict__ degi,
                                                  float* __restrict__ dinv,
                                                  float* __restrict__ selfn,
                                                  int* __restrict__ bins, int N) {
    __shared__ int lbin[NBIN];
    int t = threadIdx.x;
    if (t < NBIN) lbin[t] = 0;
    __syncthreads();
    int n = blockIdx.x * 256 + t;
    if (n < N) {
        int dg = degi[n];
        float d = 1.0f + (float)dg;
        dinv[n] = 1.0f / sqrtf(d);
        selfn[n] = 1.0f / d;
        atomicAdd(&lbin[min(dg, NBIN - 1)], 1);
    }
    __syncthreads();
    if (t < NBIN && lbin[t] > 0) atomicAdd(&bins[t], lbin[t]);
}

// ---------------- bin prefix (one wave, shfl scan over 128 bins) ----------------
__global__ void k_binscan(const int* __restrict__ bins, int* __restrict__ binstart,
                          int* __restrict__ bincur, int* __restrict__ edgebase) {
    int t = threadIdx.x & 63;
    int d0 = 2 * t, d1 = 2 * t + 1;
    int a = bins[d0], b = bins[d1];
    int ea = a * d0, eb = b * d1;
    int s = a + b, es = ea + eb;
    int ps = s, pe = es;
    #pragma unroll
    for (int off = 1; off < 64; off <<= 1) {
        int u = __shfl_up(ps, off, 64);
        int v = __shfl_up(pe, off, 64);
        if (t >= off) { ps += u; pe += v; }
    }
    int exs = ps - s, exe = pe - es;
    binstart[d0] = exs;     bincur[d0] = exs;     edgebase[d0] = exe;
    binstart[d1] = exs + a; bincur[d1] = exs + a; edgebase[d1] = exe + ea;
}

// ---------------- parallel slot assignment; emits per-slot meta + per-NODE fill meta ----------
// invmeta[n] = {edata_base, stride, bits(dinv[n]), 0} (R7 win).
__global__ __launch_bounds__(256) void k_assign(const int* __restrict__ degi,
                                                const int* __restrict__ binstart,
                                                const int* __restrict__ edgebase,
                                                const int* __restrict__ bins,
                                                int* __restrict__ bincur,
                                                const float* __restrict__ dinv,
                                                int* __restrict__ perm,
                                                int4* __restrict__ invmeta,
                                                int2* __restrict__ meta,
                                                int N) {
    __shared__ int lbin[NBIN];
    __shared__ int lbase[NBIN];
    int t = threadIdx.x;
    if (t < NBIN) lbin[t] = 0;
    __syncthreads();
    int n = blockIdx.x * 256 + t;
    int d = 0, lrank = 0;
    if (n < N) {
        d = min(degi[n], NBIN - 1);
        lrank = atomicAdd(&lbin[d], 1);
    }
    __syncthreads();
    if (t < NBIN && lbin[t] > 0) lbase[t] = atomicAdd(&bincur[t], lbin[t]);
    __syncthreads();
    if (n < N) {
        int slot = lbase[d] + lrank;
        int base = edgebase[d] + (slot - binstart[d]);
        perm[slot] = n;
        int2 m;
        m.x = base;
        m.y = bins[d] | (d << 20);
        meta[slot] = m;
        int4 im;
        im.x = base;
        im.y = bins[d];
        im.z = __float_as_int(dinv[n]);
        im.w = 0;
        invmeta[n] = im;
    }
}

// ---------------- CSR fill (atomic-free scatter: rank precomputed in deg pass) --------
// Chain: {dst->invmeta} || {erank} || {src->dinv[s]} -> store. Depth 2 (R12).
// record = (fp16(dinv[s]*dinv[d]) << 16) | src   (src < 65536 fits 16 bits)
__global__ __launch_bounds__(256) void k_fill(const int* __restrict__ src,
                                              const int* __restrict__ dst,
                                              const float* __restrict__ dinv,
                                              const int4* __restrict__ invmeta,
                                              const int* __restrict__ erank,
                                              unsigned int* __restrict__ edata) {
    int e = blockIdx.x * 256 + threadIdx.x;
    if (e >= N_EDGES) return;
    int s = src[e], d = dst[e];
    int4 im = invmeta[d];               // base | stride | dinv[d]
    int j = erank[e];
    float wdd = __int_as_float(im.z);
    float wss = dinv[s];
    int pos = im.x + j * im.y;
    _Float16 hw = (_Float16)(wss * wdd);     // RTN
    edata[pos] = ((unsigned int)__builtin_bit_cast(unsigned short, hw) << 16) |
                 (unsigned int)s;
}

// ---------------- MFMA fp16 direct GEMM, 16x128 wave tiles (2x waves) ----------
// R13 diagnosis: GEMM was GRID-limited — 3128 waves = 12/CU, occupancy 20%,
// MfmaUtil 4.9%. Fix: shrink wave tile 64x64 -> 16x128 (acc[8]) doubling waves
// to 6256 (~24/CU). A traffic unchanged (cols still 2 halves, L2-absorbed);
// extra W re-reads are L2/L1 hits (W = 128KB). No LDS, no barriers.
// Per-output accumulation order unchanged -> bit-identical results.
__global__ __launch_bounds__(256) void k_gemm(const _Float16* __restrict__ A,
                                              const _Float16* __restrict__ Wh,
                                              const float* __restrict__ bnscale,
                                              const float* __restrict__ bnshift,
                                              _Float16* __restrict__ X16, int K) {
    int tid = threadIdx.x;
    int lane = tid & 63;
    int w = tid >> 6;                    // 4 row sub-tiles per block
    int row0 = blockIdx.x * 64 + w * 16;
    int col0 = blockIdx.y * 128;
    int m = lane & 15, q = lane >> 4;

    f32x4 acc[8] = {};

    const _Float16* Abase = A + (size_t)(row0 + m) * K + q * 8;
    const _Float16* Wbase = Wh + (size_t)(col0 + m) * K + q * 8;

    for (int k0 = 0; k0 < K; k0 += 32) {
        f16x8 af = *(const f16x8*)(Abase + k0);
        f16x8 whf[8];
        #pragma unroll
        for (int c = 0; c < 8; ++c)
            whf[c] = *(const f16x8*)(Wbase + (size_t)(c * 16) * K + k0);
        #pragma unroll
        for (int c = 0; c < 8; ++c)
            acc[c] = __builtin_amdgcn_mfma_f32_16x16x32_f16(af, whf[c], acc[c], 0, 0, 0);
    }

    int mrow = row0 + q * 4;
    #pragma unroll
    for (int c = 0; c < 8; ++c) {
        int n = col0 + c * 16 + m;
        float sc = bnscale[n];
        float sh = bnshift[n];
        f32x4 v = acc[c];
        _Float16* base = X16 + (size_t)(n >> 5) * (N_NODES * 32) + (n & 31);
        #pragma unroll
        for (int g = 0; g < 4; ++g)
            if (mrow + g < N_NODES)
                base[(size_t)(mrow + g) * 32] =
                    (_Float16)fmaxf(fmaf(v[g], sc, sh), 0.f);
    }
}

// ---------------- chunked gather on fp16 X: Âx -> fp16 A node-major ----------------
// R7 form (proven best). ONE chunk/block (R8: 2 chunks blew per-XCD L2). One slot
// per quad (R9: pairing wasted issue). 8-deep unroll; packed 4B records; edata
// loads PLAIN (R1); longest-first nb order (R4/R5 win).
#define GNB 782  // ceil(50000/64) slot-blocks per chunk

__global__ __launch_bounds__(256) void k_gather(const _Float16* __restrict__ Xc,
                                                const int2* __restrict__ meta,
                                                const unsigned int* __restrict__ edata,
                                                const int* __restrict__ perm,
                                                const float* __restrict__ selfn,
                                                _Float16* __restrict__ A,
                                                int K, int cshift) {
    int bid = blockIdx.x;
    int chunk = bid & ((1 << cshift) - 1);
    int nb = (GNB - 1) - (bid >> cshift);   // longest-work-first
    const _Float16* Hc = Xc + (size_t)chunk * (N_NODES * 32);
    int slot = nb * 64 + (threadIdx.x >> 2);
    if (slot >= N_NODES) return;
    int node = perm[slot];
    int2 m = meta[slot];
    int q8 = (threadIdx.x & 3) * 8;

    int stride = m.y & 0xFFFFF;
    int deg = m.y >> 20;
    const unsigned int* ep = edata + m.x;
    float sn = selfn[node];

    float acc[8];
    {
        f16x8 hv = *(const f16x8*)(Hc + (size_t)node * 32 + q8);
        #pragma unroll
        for (int i = 0; i < 8; ++i) acc[i] = (float)hv[i] * sn;
    }

    int j = 0;
    for (; j + 7 < deg; j += 8) {
        unsigned int e[8];
        #pragma unroll
        for (int i = 0; i < 8; ++i)
            e[i] = ep[(size_t)(j + i) * stride];
        f16x8 a[8];
        #pragma unroll
        for (int i = 0; i < 8; ++i)
            a[i] = *(const f16x8*)(Hc + (size_t)(e[i] & 0xFFFFu) * 32 + q8);
        #pragma unroll
        for (int i = 0; i < 8; ++i) {
            float w = (float)__builtin_bit_cast(_Float16, (unsigned short)(e[i] >> 16));
            #pragma unroll
            for (int c = 0; c < 8; ++c) acc[c] = fmaf((float)a[i][c], w, acc[c]);
        }
    }
    if (j + 3 < deg) {
        unsigned int e[4];
        #pragma unroll
        for (int i = 0; i < 4; ++i)
            e[i] = ep[(size_t)(j + i) * stride];
        f16x8 a[4];
        #pragma unroll
        for (int i = 0; i < 4; ++i)
            a[i] = *(const f16x8*)(Hc + (size_t)(e[i] & 0xFFFFu) * 32 + q8);
        #pragma unroll
        for (int i = 0; i < 4; ++i) {
            float w = (float)__builtin_bit_cast(_Float16, (unsigned short)(e[i] >> 16));
            #pragma unroll
            for (int c = 0; c < 8; ++c) acc[c] = fmaf((float)a[i][c], w, acc[c]);
        }
        j += 4;
    }
    for (; j < deg; ++j) {
        unsigned int e0 = ep[(size_t)j * stride];
        f16x8 a0 = *(const f16x8*)(Hc + (size_t)(e0 & 0xFFFFu) * 32 + q8);
        float w0 = (float)__builtin_bit_cast(_Float16, (unsigned short)(e0 >> 16));
        #pragma unroll
        for (int i = 0; i < 8; ++i) acc[i] = fmaf((float)a0[i], w0, acc[i]);
    }

    f16x8 o;
    #pragma unroll
    for (int i = 0; i < 8; ++i) o[i] = (_Float16)acc[i];
    u32x4 uv = *(u32x4*)&o;
    __builtin_nontemporal_store(uv, (u32x4*)(A + (size_t)node * K + chunk * 32 + q8));
}

// ---------------- fused mean-pool + MLP head (one block per graph) ----------------
// R12: 4-way node unroll — 8 independent accumulator chains instead of 1 serial walk.
__global__ __launch_bounds__(128) void k_poolmlp(const _Float16* __restrict__ X16,
                                                 const int* __restrict__ gstart,
                                                 const int* __restrict__ gend,
                                                 const float* __restrict__ W1,
                                                 const float* __restrict__ b1,
                                                 const float* __restrict__ W2,
                                                 const float* __restrict__ b2,
                                                 float* __restrict__ out) {
    __shared__ float prow[HID];
    __shared__ float hred[2];
    int g = blockIdx.x;
    int s = gstart[g], e = gend[g];
    int j = threadIdx.x; // 0..127, channels j and j+128
    const _Float16* p0 = X16 + (size_t)(j >> 5) * (N_NODES * 32) + (j & 31);
    const _Float16* p1 = X16 + (size_t)((j >> 5) + 4) * (N_NODES * 32) + (j & 31);
    float a0 = 0.f, a1 = 0.f, b0 = 0.f, b1v = 0.f, c0 = 0.f, c1 = 0.f, d0 = 0.f, d1 = 0.f;
    int n = s;
    for (; n + 3 < e; n += 4) {
        a0 += (float)p0[(size_t)n * 32];
        a1 += (float)p1[(size_t)n * 32];
        b0 += (float)p0[(size_t)(n + 1) * 32];
        b1v += (float)p1[(size_t)(n + 1) * 32];
        c0 += (float)p0[(size_t)(n + 2) * 32];
        c1 += (float)p1[(size_t)(n + 2) * 32];
        d0 += (float)p0[(size_t)(n + 3) * 32];
        d1 += (float)p1[(size_t)(n + 3) * 32];
    }
    for (; n < e; ++n) {
        a0 += (float)p0[(size_t)n * 32];
        a1 += (float)p1[(size_t)n * 32];
    }
    a0 = (a0 + b0) + (c0 + d0);
    a1 = (a1 + b1v) + (c1 + d1);
    float inv = 1.0f / fmaxf((float)(e - s), 1.0f);
    prow[j] = a0 * inv;
    prow[j + 128] = a1 * inv;
    __syncthreads();
    float acc = 0.f;
    #pragma unroll 8
    for (int k = 0; k < HID; ++k) acc += prow[k] * W1[k * 128 + j];
    float h = fmaxf(acc + b1[j], 0.f);
    float p = h * W2[j];
    #pragma unroll
    for (int off = 32; off > 0; off >>= 1) p += __shfl_down(p, off, 64);
    if ((j & 63) == 0) hred[j >> 6] = p;
    __syncthreads();
    if (j == 0) out[g] = hred[0] + hred[1] + b2[0];
}

extern "C" void kernel_launch(void* const* d_in, const int* in_sizes, int n_in,
                              void* d_out, int out_size, void* d_ws, size_t ws_size,
                              hipStream_t stream) {
    const float* x      = (const float*)d_in[0];
    const int*   ei     = (const int*)d_in[1];
    const int*   batch  = (const int*)d_in[2];
    const float* convW0 = (const float*)d_in[3];
    const float* convWs = (const float*)d_in[4];
    const float* convB  = (const float*)d_in[5];
    const float* gamma  = (const float*)d_in[6];
    const float* beta   = (const float*)d_in[7];
    const float* mean   = (const float*)d_in[8];
    const float* var    = (const float*)d_in[9];
    const float* lin1W  = (const float*)d_in[10];
    const float* lin1b  = (const float*)d_in[11];
    const float* lin2W  = (const float*)d_in[12];
    const float* lin2b  = (const float*)d_in[13];
    float* out = (float*)d_out;

    const int* src = ei;
    const int* dst = ei + N_EDGES;

    const int WTOT = 128 * 256 + 3 * 256 * 256; // 229376

    char* wsb = (char*)d_ws;
    _Float16* x16a = (_Float16*)wsb;                     // N*HID fp16 (ping)
    _Float16* x16b = x16a + (size_t)N_NODES * HID;       // N*HID fp16 (pong)
    _Float16* Ab   = x16b + (size_t)N_NODES * HID;       // N*HID fp16 (GEMM A operand)
    _Float16* Wh16 = Ab + (size_t)N_NODES * HID;         // WTOT fp16
    _Float16* Wl16 = Wh16 + WTOT;                        // WTOT fp16 (unused, kept for layout)
    float* dinv    = (float*)(Wl16 + WTOT);              // N
    float* selfn   = dinv + N_NODES;                     // N
    float* bnscale = selfn + N_NODES;                    // 4*HID
    float* bnshift = bnscale + N_LAYERS * HID;           // 4*HID
    // contiguous zero-init region: degi | bins | gstart | gend
    int*   degi    = (int*)(bnshift + N_LAYERS * HID);   // N
    int*   bins    = degi + N_NODES;                     // NBIN
    int*   gstart  = bins + NBIN;                        // G
    int*   gend    = gstart + N_GRAPHS;                  // G
    int*   binstart= gend + N_GRAPHS;                    // NBIN
    int*   bincur  = binstart + NBIN;                    // NBIN
    int*   edgebase= bincur + NBIN;                      // NBIN
    int*   perm    = edgebase + NBIN;                    // N
    int2*  meta    = (int2*)(perm + N_NODES);            // N int2
    int4*  invmeta = (int4*)(meta + N_NODES);            // N int4 (per-node fill meta)
    int*   erank   = (int*)(invmeta + N_NODES);          // E (edge rank within dst)
    unsigned int* edata = (unsigned int*)(erank + N_EDGES); // E u32 (packed)

    hipMemsetAsync(degi, 0, (size_t)(N_NODES + NBIN + 2 * N_GRAPHS) * 4, stream);

    // CSR build + norms + degree sort; prep fused under degbounds (R11); erank (R12)
    const int PREP_TOT = N_LAYERS * HID + WTOT + N_NODES * IN_DIM / 4;
    const int PREP_BLKS = (PREP_TOT + 255) / 256;
    k_degboundsprep<<<EDGE_BLKS + NODE_BLKS + PREP_BLKS, 256, 0, stream>>>(
        dst, degi, erank, batch, gstart, gend,
        gamma, beta, mean, var, convB, convW0, convWs, x,
        bnscale, bnshift, Wh16, x16a);
    k_nodeprep<<<NODE_BLKS, 256, 0, stream>>>(degi, dinv, selfn, bins, N_NODES);
    k_binscan<<<1, 64, 0, stream>>>(bins, binstart, bincur, edgebase);
    k_assign<<<NODE_BLKS, 256, 0, stream>>>(degi, binstart, edgebase, bins, bincur, dinv,
                                            perm, invmeta, meta, N_NODES);

    // CSR fill (atomic-free scatter)
    k_fill<<<EDGE_BLKS, 256, 0, stream>>>(src, dst, dinv, invmeta, erank, edata);

    // layers: gather (Âx, fp16) -> fp16 direct GEMM 16x128 wave tiles (+BN+ReLU)
    dim3 gg((N_NODES + 63) / 64, 2);
    _Float16* cur = x16a;
    for (int l = 0; l < N_LAYERS; ++l) {
        int K = (l == 0) ? IN_DIM : HID;
        int nchunk = K / 32;
        int cshift = (l == 0) ? 2 : 3;
        size_t woff = (l == 0) ? 0 : (size_t)(32768 + (l - 1) * 65536);
        k_gather<<<nchunk * GNB, 256, 0, stream>>>(cur, meta, edata, perm, selfn,
                                                   Ab, K, cshift);
        _Float16* nxt = (cur == x16a) ? x16b : x16a;
        k_gemm<<<gg, 256, 0, stream>>>(Ab, Wh16 + woff,
                                       bnscale + l * HID, bnshift + l * HID, nxt, K);
        cur = nxt;
    }

    k_poolmlp<<<N_GRAPHS, 128, 0, stream>>>(cur, gstart, gend, lin1W, lin1b, lin2W, lin2b, out);
}

// Round 15
// 448.322 us; speedup vs baseline: 1.2202x; 1.2202x over previous
//
#include <hip/hip_runtime.h>

#define N_NODES 50000
#define N_EDGES 800000
#define N_GRAPHS 2048
#define IN_DIM 128
#define HID 256
#define N_LAYERS 4
#define BN_EPS 1e-5f
#define NBIN 128
#define WSCALE 64.0f

#define EDGE_BLKS 3125   // ceil(800000/256)
#define NODE_BLKS 196    // ceil(50000/256)

typedef unsigned short ushort_t;
typedef float f32x4 __attribute__((ext_vector_type(4)));
typedef unsigned int u32x4 __attribute__((ext_vector_type(4)));
typedef _Float16 f16x8 __attribute__((ext_vector_type(8)));
typedef _Float16 f16x4 __attribute__((ext_vector_type(4)));

// ---------------- deg count (+edge rank) + graph bounds + prep (fused grid) ----------
// R12: the deg atomic's return value IS each edge's rank within its dst group —
// store it (erank) so k_fill needs no cursor atomic at all (chain depth 3 -> 2).
__global__ __launch_bounds__(256) void k_degboundsprep(const int* __restrict__ dst,
                                                       int* __restrict__ degi,
                                                       int* __restrict__ erank,
                                                       const int* __restrict__ batch,
                                                       int* __restrict__ gstart,
                                                       int* __restrict__ gend,
                                                       const float* __restrict__ gamma,
                                                       const float* __restrict__ beta,
                                                       const float* __restrict__ mean,
                                                       const float* __restrict__ var,
                                                       const float* __restrict__ bias,
                                                       const float* __restrict__ W0,
                                                       const float* __restrict__ Ws,
                                                       const float* __restrict__ x,
                                                       float* __restrict__ scale,
                                                       float* __restrict__ shift,
                                                       _Float16* __restrict__ Wh,
                                                       _Float16* __restrict__ X16) {
    int bid = blockIdx.x;
    if (bid < EDGE_BLKS) {
        int e = bid * 256 + threadIdx.x;
        if (e < N_EDGES) erank[e] = atomicAdd(&degi[dst[e]], 1);
        return;
    }
    if (bid < EDGE_BLKS + NODE_BLKS) {
        int n = (bid - EDGE_BLKS) * 256 + threadIdx.x;
        if (n >= N_NODES) return;
        int g = batch[n];
        if (n == 0 || batch[n - 1] != g) gstart[g] = n;
        if (n == N_NODES - 1 || batch[n + 1] != g) gend[g] = n + 1;
        return;
    }
    int id = (bid - EDGE_BLKS - NODE_BLKS) * 256 + threadIdx.x;
    if (id < N_LAYERS * HID) {
        float s = gamma[id] * rsqrtf(var[id] + BN_EPS);
        scale[id] = s / WSCALE;
        shift[id] = beta[id] + (bias[id] - mean[id]) * s;
        return;
    }
    id -= N_LAYERS * HID;
    const int WT = 128 * 256 + 3 * 256 * 256;
    if (id < WT) {
        float v;
        if (id < 32768) {
            int n = id >> 7, k = id & 127;
            v = W0[k * 256 + n];
        } else {
            int t = id - 32768;
            int l = t >> 16;
            int r = t & 65535;
            int n = r >> 8, k = r & 255;
            v = Ws[l * 65536 + k * 256 + n];
        }
        Wh[id] = (_Float16)(v * WSCALE);
        return;
    }
    id -= WT;
    const int total4 = N_NODES * IN_DIM / 4;
    if (id < total4) {
        float4 v = ((const float4*)x)[id];
        int n = id >> 5;
        int c0 = (id & 31) * 4;
        f16x4 o;
        o.x = (_Float16)v.x; o.y = (_Float16)v.y; o.z = (_Float16)v.z; o.w = (_Float16)v.w;
        *(f16x4*)(X16 + (size_t)(c0 >> 5) * (N_NODES * 32) + (size_t)n * 32 + (c0 & 31)) = o;
    }
}

// ---------------- node norms + degree histogram (fused, hierarchical) ----------------
__global__ __launch_bounds__(256) void k_nodeprep(const int* __restrict__ degi,
                                                  float* __restrict__ dinv,
                                                  float* __restrict__ selfn,
                                                  int* __restrict__ bins, int N) {
    __shared__ int lbin[NBIN];
    int t = threadIdx.x;
    if (t < NBIN) lbin[t] = 0;
    __syncthreads();
    int n = blockIdx.x * 256 + t;
    if (n < N) {
        int dg = degi[n];
        float d = 1.0f + (float)dg;
        dinv[n] = 1.0f / sqrtf(d);
        selfn[n] = 1.0f / d;
        atomicAdd(&lbin[min(dg, NBIN - 1)], 1);
    }
    __syncthreads();
    if (t < NBIN && lbin[t] > 0) atomicAdd(&bins[t], lbin[t]);
}

// ---------------- bin prefix (one wave, shfl scan over 128 bins) ----------------
__global__ void k_binscan(const int* __restrict__ bins, int* __restrict__ binstart,
                          int* __restrict__ bincur, int* __restrict__ edgebase) {
    int t = threadIdx.x & 63;
    int d0 = 2 * t, d1 = 2 * t + 1;
    int a = bins[d0], b = bins[d1];
    int ea = a * d0, eb = b * d1;
    int s = a + b, es = ea + eb;
    int ps = s, pe = es;
    #pragma unroll
    for (int off = 1; off < 64; off <<= 1) {
        int u = __shfl_up(ps, off, 64);
        int v = __shfl_up(pe, off, 64);
        if (t >= off) { ps += u; pe += v; }
    }
    int exs = ps - s, exe = pe - es;
    binstart[d0] = exs;     bincur[d0] = exs;     edgebase[d0] = exe;
    binstart[d1] = exs + a; bincur[d1] = exs + a; edgebase[d1] = exe + ea;
}

// ---------------- parallel slot assignment; emits per-slot meta + per-NODE fill meta ----------
// invmeta[n] = {edata_base, stride, bits(dinv[n]), 0} (R7 win).
__global__ __launch_bounds__(256) void k_assign(const int* __restrict__ degi,
                                                const int* __restrict__ binstart,
                                                const int* __restrict__ edgebase,
                                                const int* __restrict__ bins,
                                                int* __restrict__ bincur,
                                                const float* __restrict__ dinv,
                                                int* __restrict__ perm,
                                                int4* __restrict__ invmeta,
                                                int2* __restrict__ meta,
                                                int N) {
    __shared__ int lbin[NBIN];
    __shared__ int lbase[NBIN];
    int t = threadIdx.x;
    if (t < NBIN) lbin[t] = 0;
    __syncthreads();
    int n = blockIdx.x * 256 + t;
    int d = 0, lrank = 0;
    if (n < N) {
        d = min(degi[n], NBIN - 1);
        lrank = atomicAdd(&lbin[d], 1);
    }
    __syncthreads();
    if (t < NBIN && lbin[t] > 0) lbase[t] = atomicAdd(&bincur[t], lbin[t]);
    __syncthreads();
    if (n < N) {
        int slot = lbase[d] + lrank;
        int base = edgebase[d] + (slot - binstart[d]);
        perm[slot] = n;
        int2 m;
        m.x = base;
        m.y = bins[d] | (d << 20);
        meta[slot] = m;
        int4 im;
        im.x = base;
        im.y = bins[d];
        im.z = __float_as_int(dinv[n]);
        im.w = 0;
        invmeta[n] = im;
    }
}

// ---------------- CSR fill (atomic-free scatter: rank precomputed in deg pass) --------
// Chain: {dst->invmeta} || {erank} || {src->dinv[s]} -> store. Depth 2 (R12).
// record = (fp16(dinv[s]*dinv[d]) << 16) | src   (src < 65536 fits 16 bits)
__global__ __launch_bounds__(256) void k_fill(const int* __restrict__ src,
                                              const int* __restrict__ dst,
                                              const float* __restrict__ dinv,
                                              const int4* __restrict__ invmeta,
                                              const int* __restrict__ erank,
                                              unsigned int* __restrict__ edata) {
    int e = blockIdx.x * 256 + threadIdx.x;
    if (e >= N_EDGES) return;
    int s = src[e], d = dst[e];
    int4 im = invmeta[d];               // base | stride | dinv[d]
    int j = erank[e];
    float wdd = __int_as_float(im.z);
    float wss = dinv[s];
    int pos = im.x + j * im.y;
    _Float16 hw = (_Float16)(wss * wdd);     // RTN
    edata[pos] = ((unsigned int)__builtin_bit_cast(unsigned short, hw) << 16) |
                 (unsigned int)s;
}

// ---------------- MFMA fp16 GEMM: W-resident-in-LDS, streaming A ----------------
// R15 synthesis of R13/R14 failures: per-k-step operand delivery is the cost.
// W half-tile (128 cols x K = 64KB) fits LDS ONCE per block: stage it with one
// barrier (seg-XOR swizzle, R11's proven conflict-free read scheme), then every
// wave streams its A rows from global (coalesced) with ZERO further barriers —
// 1 A load + 8 ds_read + 8 MFMA per k-step. Traffic floor ~12-15us/layer.
// Per-output accumulation order unchanged -> bit-identical results.
__global__ __launch_bounds__(256) void k_gemm(const _Float16* __restrict__ A,
                                              const _Float16* __restrict__ Wh,
                                              const float* __restrict__ bnscale,
                                              const float* __restrict__ bnshift,
                                              _Float16* __restrict__ X16, int K) {
    __shared__ _Float16 sw[128 * 32 * 8]; // 64KB max (K=256); K=128 uses half
    int tid = threadIdx.x;
    int lane = tid & 63;
    int w = tid >> 6;
    int segs = K >> 3;                    // 32 (K=256) or 16 (K=128)
    int sshift = (K == 256) ? 5 : 4;
    int col0 = blockIdx.y * 128;

    // one-time W stage: seg s of col swizzled to s^(col&7)
    int cnt = K >> 4;                     // segs per thread
    for (int i = 0; i < cnt; ++i) {
        int g = tid * cnt + i;
        int col = g >> sshift;
        int s = g & (segs - 1);
        f16x8 v = *(const f16x8*)(Wh + (size_t)(col0 + col) * K + s * 8);
        *(f16x8*)(sw + ((size_t)col << (sshift + 3)) + ((s ^ (col & 7)) << 3)) = v;
    }
    __syncthreads();

    int m = lane & 15, q = lane >> 4;
    int rw0 = blockIdx.x * 128 + w * 32;

    #pragma unroll
    for (int strip = 0; strip < 2; ++strip) {
        int row0 = rw0 + strip * 16;
        f32x4 acc[8] = {};
        const _Float16* Abase = A + (size_t)(row0 + m) * K + q * 8;
        for (int k0 = 0; k0 < K; k0 += 32) {
            f16x8 af = *(const f16x8*)(Abase + k0);
            int sbase = (k0 >> 3) + q;
            #pragma unroll
            for (int c = 0; c < 8; ++c) {
                int col = c * 16 + m;
                f16x8 whf = *(const f16x8*)(sw + (col << (sshift + 3)) +
                                            ((sbase ^ (col & 7)) << 3));
                acc[c] = __builtin_amdgcn_mfma_f32_16x16x32_f16(af, whf, acc[c], 0, 0, 0);
            }
        }
        int mrow = row0 + q * 4;
        #pragma unroll
        for (int c = 0; c < 8; ++c) {
            int n = col0 + c * 16 + m;
            float sc = bnscale[n];
            float sh = bnshift[n];
            f32x4 v = acc[c];
            _Float16* base = X16 + (size_t)(n >> 5) * (N_NODES * 32) + (n & 31);
            #pragma unroll
            for (int g = 0; g < 4; ++g)
                if (mrow + g < N_NODES)
                    base[(size_t)(mrow + g) * 32] =
                        (_Float16)fmaxf(fmaf(v[g], sc, sh), 0.f);
        }
    }
}

// ---------------- chunked gather on fp16 X: Âx -> fp16 A node-major ----------------
// R7 form (proven best). ONE chunk/block (R8: 2 chunks blew per-XCD L2). One slot
// per quad (R9: pairing wasted issue). 8-deep unroll; packed 4B records; edata
// loads PLAIN (R1); longest-first nb order (R4/R5 win).
#define GNB 782  // ceil(50000/64) slot-blocks per chunk

__global__ __launch_bounds__(256) void k_gather(const _Float16* __restrict__ Xc,
                                                const int2* __restrict__ meta,
                                                const unsigned int* __restrict__ edata,
                                                const int* __restrict__ perm,
                                                const float* __restrict__ selfn,
                                                _Float16* __restrict__ A,
                                                int K, int cshift) {
    int bid = blockIdx.x;
    int chunk = bid & ((1 << cshift) - 1);
    int nb = (GNB - 1) - (bid >> cshift);   // longest-work-first
    const _Float16* Hc = Xc + (size_t)chunk * (N_NODES * 32);
    int slot = nb * 64 + (threadIdx.x >> 2);
    if (slot >= N_NODES) return;
    int node = perm[slot];
    int2 m = meta[slot];
    int q8 = (threadIdx.x & 3) * 8;

    int stride = m.y & 0xFFFFF;
    int deg = m.y >> 20;
    const unsigned int* ep = edata + m.x;
    float sn = selfn[node];

    float acc[8];
    {
        f16x8 hv = *(const f16x8*)(Hc + (size_t)node * 32 + q8);
        #pragma unroll
        for (int i = 0; i < 8; ++i) acc[i] = (float)hv[i] * sn;
    }

    int j = 0;
    for (; j + 7 < deg; j += 8) {
        unsigned int e[8];
        #pragma unroll
        for (int i = 0; i < 8; ++i)
            e[i] = ep[(size_t)(j + i) * stride];
        f16x8 a[8];
        #pragma unroll
        for (int i = 0; i < 8; ++i)
            a[i] = *(const f16x8*)(Hc + (size_t)(e[i] & 0xFFFFu) * 32 + q8);
        #pragma unroll
        for (int i = 0; i < 8; ++i) {
            float w = (float)__builtin_bit_cast(_Float16, (unsigned short)(e[i] >> 16));
            #pragma unroll
            for (int c = 0; c < 8; ++c) acc[c] = fmaf((float)a[i][c], w, acc[c]);
        }
    }
    if (j + 3 < deg) {
        unsigned int e[4];
        #pragma unroll
        for (int i = 0; i < 4; ++i)
            e[i] = ep[(size_t)(j + i) * stride];
        f16x8 a[4];
        #pragma unroll
        for (int i = 0; i < 4; ++i)
            a[i] = *(const f16x8*)(Hc + (size_t)(e[i] & 0xFFFFu) * 32 + q8);
        #pragma unroll
        for (int i = 0; i < 4; ++i) {
            float w = (float)__builtin_bit_cast(_Float16, (unsigned short)(e[i] >> 16));
            #pragma unroll
            for (int c = 0; c < 8; ++c) acc[c] = fmaf((float)a[i][c], w, acc[c]);
        }
        j += 4;
    }
    for (; j < deg; ++j) {
        unsigned int e0 = ep[(size_t)j * stride];
        f16x8 a0 = *(const f16x8*)(Hc + (size_t)(e0 & 0xFFFFu) * 32 + q8);
        float w0 = (float)__builtin_bit_cast(_Float16, (unsigned short)(e0 >> 16));
        #pragma unroll
        for (int i = 0; i < 8; ++i) acc[i] = fmaf((float)a0[i], w0, acc[i]);
    }

    f16x8 o;
    #pragma unroll
    for (int i = 0; i < 8; ++i) o[i] = (_Float16)acc[i];
    u32x4 uv = *(u32x4*)&o;
    __builtin_nontemporal_store(uv, (u32x4*)(A + (size_t)node * K + chunk * 32 + q8));
}

// ---------------- fused mean-pool + MLP head (one block per graph) ----------------
// R12: 4-way node unroll — independent accumulator chains instead of 1 serial walk.
__global__ __launch_bounds__(128) void k_poolmlp(const _Float16* __restrict__ X16,
                                                 const int* __restrict__ gstart,
                                                 const int* __restrict__ gend,
                                                 const float* __restrict__ W1,
                                                 const float* __restrict__ b1,
                                                 const float* __restrict__ W2,
                                                 const float* __restrict__ b2,
                                                 float* __restrict__ out) {
    __shared__ float prow[HID];
    __shared__ float hred[2];
    int g = blockIdx.x;
    int s = gstart[g], e = gend[g];
    int j = threadIdx.x; // 0..127, channels j and j+128
    const _Float16* p0 = X16 + (size_t)(j >> 5) * (N_NODES * 32) + (j & 31);
    const _Float16* p1 = X16 + (size_t)((j >> 5) + 4) * (N_NODES * 32) + (j & 31);
    float a0 = 0.f, a1 = 0.f, b0 = 0.f, b1v = 0.f, c0 = 0.f, c1 = 0.f, d0 = 0.f, d1 = 0.f;
    int n = s;
    for (; n + 3 < e; n += 4) {
        a0 += (float)p0[(size_t)n * 32];
        a1 += (float)p1[(size_t)n * 32];
        b0 += (float)p0[(size_t)(n + 1) * 32];
        b1v += (float)p1[(size_t)(n + 1) * 32];
        c0 += (float)p0[(size_t)(n + 2) * 32];
        c1 += (float)p1[(size_t)(n + 2) * 32];
        d0 += (float)p0[(size_t)(n + 3) * 32];
        d1 += (float)p1[(size_t)(n + 3) * 32];
    }
    for (; n < e; ++n) {
        a0 += (float)p0[(size_t)n * 32];
        a1 += (float)p1[(size_t)n * 32];
    }
    a0 = (a0 + b0) + (c0 + d0);
    a1 = (a1 + b1v) + (c1 + d1);
    float inv = 1.0f / fmaxf((float)(e - s), 1.0f);
    prow[j] = a0 * inv;
    prow[j + 128] = a1 * inv;
    __syncthreads();
    float acc = 0.f;
    #pragma unroll 8
    for (int k = 0; k < HID; ++k) acc += prow[k] * W1[k * 128 + j];
    float h = fmaxf(acc + b1[j], 0.f);
    float p = h * W2[j];
    #pragma unroll
    for (int off = 32; off > 0; off >>= 1) p += __shfl_down(p, off, 64);
    if ((j & 63) == 0) hred[j >> 6] = p;
    __syncthreads();
    if (j == 0) out[g] = hred[0] + hred[1] + b2[0];
}

extern "C" void kernel_launch(void* const* d_in, const int* in_sizes, int n_in,
                              void* d_out, int out_size, void* d_ws, size_t ws_size,
                              hipStream_t stream) {
    const float* x      = (const float*)d_in[0];
    const int*   ei     = (const int*)d_in[1];
    const int*   batch  = (const int*)d_in[2];
    const float* convW0 = (const float*)d_in[3];
    const float* convWs = (const float*)d_in[4];
    const float* convB  = (const float*)d_in[5];
    const float* gamma  = (const float*)d_in[6];
    const float* beta   = (const float*)d_in[7];
    const float* mean   = (const float*)d_in[8];
    const float* var    = (const float*)d_in[9];
    const float* lin1W  = (const float*)d_in[10];
    const float* lin1b  = (const float*)d_in[11];
    const float* lin2W  = (const float*)d_in[12];
    const float* lin2b  = (const float*)d_in[13];
    float* out = (float*)d_out;

    const int* src = ei;
    const int* dst = ei + N_EDGES;

    const int WTOT = 128 * 256 + 3 * 256 * 256; // 229376

    char* wsb = (char*)d_ws;
    _Float16* x16a = (_Float16*)wsb;                     // N*HID fp16 (ping)
    _Float16* x16b = x16a + (size_t)N_NODES * HID;       // N*HID fp16 (pong)
    _Float16* Ab   = x16b + (size_t)N_NODES * HID;       // N*HID fp16 (GEMM A operand)
    _Float16* Wh16 = Ab + (size_t)N_NODES * HID;         // WTOT fp16
    _Float16* Wl16 = Wh16 + WTOT;                        // WTOT fp16 (unused, kept for layout)
    float* dinv    = (float*)(Wl16 + WTOT);              // N
    float* selfn   = dinv + N_NODES;                     // N
    float* bnscale = selfn + N_NODES;                    // 4*HID
    float* bnshift = bnscale + N_LAYERS * HID;           // 4*HID
    // contiguous zero-init region: degi | bins | gstart | gend
    int*   degi    = (int*)(bnshift + N_LAYERS * HID);   // N
    int*   bins    = degi + N_NODES;                     // NBIN
    int*   gstart  = bins + NBIN;                        // G
    int*   gend    = gstart + N_GRAPHS;                  // G
    int*   binstart= gend + N_GRAPHS;                    // NBIN
    int*   bincur  = binstart + NBIN;                    // NBIN
    int*   edgebase= bincur + NBIN;                      // NBIN
    int*   perm    = edgebase + NBIN;                    // N
    int2*  meta    = (int2*)(perm + N_NODES);            // N int2
    int4*  invmeta = (int4*)(meta + N_NODES);            // N int4 (per-node fill meta)
    int*   erank   = (int*)(invmeta + N_NODES);          // E (edge rank within dst)
    unsigned int* edata = (unsigned int*)(erank + N_EDGES); // E u32 (packed)

    hipMemsetAsync(degi, 0, (size_t)(N_NODES + NBIN + 2 * N_GRAPHS) * 4, stream);

    // CSR build + norms + degree sort; prep fused under degbounds (R11); erank (R12)
    const int PREP_TOT = N_LAYERS * HID + WTOT + N_NODES * IN_DIM / 4;
    const int PREP_BLKS = (PREP_TOT + 255) / 256;
    k_degboundsprep<<<EDGE_BLKS + NODE_BLKS + PREP_BLKS, 256, 0, stream>>>(
        dst, degi, erank, batch, gstart, gend,
        gamma, beta, mean, var, convB, convW0, convWs, x,
        bnscale, bnshift, Wh16, x16a);
    k_nodeprep<<<NODE_BLKS, 256, 0, stream>>>(degi, dinv, selfn, bins, N_NODES);
    k_binscan<<<1, 64, 0, stream>>>(bins, binstart, bincur, edgebase);
    k_assign<<<NODE_BLKS, 256, 0, stream>>>(degi, binstart, edgebase, bins, bincur, dinv,
                                            perm, invmeta, meta, N_NODES);

    // CSR fill (atomic-free scatter)
    k_fill<<<EDGE_BLKS, 256, 0, stream>>>(src, dst, dinv, invmeta, erank, edata);

    // layers: gather (Âx, fp16) -> W-in-LDS streaming GEMM (+BN+ReLU, fp16 out)
    dim3 gg((N_NODES + 127) / 128, 2);
    _Float16* cur = x16a;
    for (int l = 0; l < N_LAYERS; ++l) {
        int K = (l == 0) ? IN_DIM : HID;
        int nchunk = K / 32;
        int cshift = (l == 0) ? 2 : 3;
        size_t woff = (l == 0) ? 0 : (size_t)(32768 + (l - 1) * 65536);
        k_gather<<<nchunk * GNB, 256, 0, stream>>>(cur, meta, edata, perm, selfn,
                                                   Ab, K, cshift);
        _Float16* nxt = (cur == x16a) ? x16b : x16a;
        k_gemm<<<gg, 256, 0, stream>>>(Ab, Wh16 + woff,
                                       bnscale + l * HID, bnshift + l * HID, nxt, K);
        cur = nxt;
    }

    k_poolmlp<<<N_GRAPHS, 128, 0, stream>>>(cur, gstart, gend, lin1W, lin1b, lin2W, lin2b, out);
}

// Round 16
// 433.400 us; speedup vs baseline: 1.2622x; 1.0344x over previous
//
#include <hip/hip_runtime.h>

#define N_NODES 50000
#define N_EDGES 800000
#define N_GRAPHS 2048
#define IN_DIM 128
#define HID 256
#define N_LAYERS 4
#define BN_EPS 1e-5f
#define NBIN 128
#define WSCALE 64.0f

#define EDGE_BLKS 3125   // ceil(800000/256)
#define NODE_BLKS 196    // ceil(50000/256)

typedef unsigned short ushort_t;
typedef float f32x4 __attribute__((ext_vector_type(4)));
typedef unsigned int u32x4 __attribute__((ext_vector_type(4)));
typedef _Float16 f16x8 __attribute__((ext_vector_type(8)));
typedef _Float16 f16x4 __attribute__((ext_vector_type(4)));

// ---------------- deg count (+edge rank) + graph bounds + prep (fused grid) ----------
// R12: the deg atomic's return value IS each edge's rank within its dst group —
// store it (erank) so k_fill needs no cursor atomic at all (chain depth 3 -> 2).
__global__ __launch_bounds__(256) void k_degboundsprep(const int* __restrict__ dst,
                                                       int* __restrict__ degi,
                                                       int* __restrict__ erank,
                                                       const int* __restrict__ batch,
                                                       int* __restrict__ gstart,
                                                       int* __restrict__ gend,
                                                       const float* __restrict__ gamma,
                                                       const float* __restrict__ beta,
                                                       const float* __restrict__ mean,
                                                       const float* __restrict__ var,
                                                       const float* __restrict__ bias,
                                                       const float* __restrict__ W0,
                                                       const float* __restrict__ Ws,
                                                       const float* __restrict__ x,
                                                       float* __restrict__ scale,
                                                       float* __restrict__ shift,
                                                       _Float16* __restrict__ Wh,
                                                       _Float16* __restrict__ X16) {
    int bid = blockIdx.x;
    if (bid < EDGE_BLKS) {
        int e = bid * 256 + threadIdx.x;
        if (e < N_EDGES) erank[e] = atomicAdd(&degi[dst[e]], 1);
        return;
    }
    if (bid < EDGE_BLKS + NODE_BLKS) {
        int n = (bid - EDGE_BLKS) * 256 + threadIdx.x;
        if (n >= N_NODES) return;
        int g = batch[n];
        if (n == 0 || batch[n - 1] != g) gstart[g] = n;
        if (n == N_NODES - 1 || batch[n + 1] != g) gend[g] = n + 1;
        return;
    }
    int id = (bid - EDGE_BLKS - NODE_BLKS) * 256 + threadIdx.x;
    if (id < N_LAYERS * HID) {
        float s = gamma[id] * rsqrtf(var[id] + BN_EPS);
        scale[id] = s / WSCALE;
        shift[id] = beta[id] + (bias[id] - mean[id]) * s;
        return;
    }
    id -= N_LAYERS * HID;
    const int WT = 128 * 256 + 3 * 256 * 256;
    if (id < WT) {
        float v;
        if (id < 32768) {
            int n = id >> 7, k = id & 127;
            v = W0[k * 256 + n];
        } else {
            int t = id - 32768;
            int l = t >> 16;
            int r = t & 65535;
            int n = r >> 8, k = r & 255;
            v = Ws[l * 65536 + k * 256 + n];
        }
        Wh[id] = (_Float16)(v * WSCALE);
        return;
    }
    id -= WT;
    const int total4 = N_NODES * IN_DIM / 4;
    if (id < total4) {
        float4 v = ((const float4*)x)[id];
        int n = id >> 5;
        int c0 = (id & 31) * 4;
        f16x4 o;
        o.x = (_Float16)v.x; o.y = (_Float16)v.y; o.z = (_Float16)v.z; o.w = (_Float16)v.w;
        *(f16x4*)(X16 + (size_t)(c0 >> 5) * (N_NODES * 32) + (size_t)n * 32 + (c0 & 31)) = o;
    }
}

// ---------------- node norms + degree histogram (fused, hierarchical) ----------------
__global__ __launch_bounds__(256) void k_nodeprep(const int* __restrict__ degi,
                                                  float* __restrict__ dinv,
                                                  float* __restrict__ selfn,
                                                  int* __restrict__ bins, int N) {
    __shared__ int lbin[NBIN];
    int t = threadIdx.x;
    if (t < NBIN) lbin[t] = 0;
    __syncthreads();
    int n = blockIdx.x * 256 + t;
    if (n < N) {
        int dg = degi[n];
        float d = 1.0f + (float)dg;
        dinv[n] = 1.0f / sqrtf(d);
        selfn[n] = 1.0f / d;
        atomicAdd(&lbin[min(dg, NBIN - 1)], 1);
    }
    __syncthreads();
    if (t < NBIN && lbin[t] > 0) atomicAdd(&bins[t], lbin[t]);
}

// ---------------- bin prefix (one wave, shfl scan over 128 bins) ----------------
__global__ void k_binscan(const int* __restrict__ bins, int* __restrict__ binstart,
                          int* __restrict__ bincur, int* __restrict__ edgebase) {
    int t = threadIdx.x & 63;
    int d0 = 2 * t, d1 = 2 * t + 1;
    int a = bins[d0], b = bins[d1];
    int ea = a * d0, eb = b * d1;
    int s = a + b, es = ea + eb;
    int ps = s, pe = es;
    #pragma unroll
    for (int off = 1; off < 64; off <<= 1) {
        int u = __shfl_up(ps, off, 64);
        int v = __shfl_up(pe, off, 64);
        if (t >= off) { ps += u; pe += v; }
    }
    int exs = ps - s, exe = pe - es;
    binstart[d0] = exs;     bincur[d0] = exs;     edgebase[d0] = exe;
    binstart[d1] = exs + a; bincur[d1] = exs + a; edgebase[d1] = exe + ea;
}

// ---------------- parallel slot assignment; emits per-slot meta + per-NODE fill meta ----------
// invmeta[n] = {edata_base, stride, bits(dinv[n]), 0} (R7 win).
__global__ __launch_bounds__(256) void k_assign(const int* __restrict__ degi,
                                                const int* __restrict__ binstart,
                                                const int* __restrict__ edgebase,
                                                const int* __restrict__ bins,
                                                int* __restrict__ bincur,
                                                const float* __restrict__ dinv,
                                                int* __restrict__ perm,
                                                int4* __restrict__ invmeta,
                                                int2* __restrict__ meta,
                                                int N) {
    __shared__ int lbin[NBIN];
    __shared__ int lbase[NBIN];
    int t = threadIdx.x;
    if (t < NBIN) lbin[t] = 0;
    __syncthreads();
    int n = blockIdx.x * 256 + t;
    int d = 0, lrank = 0;
    if (n < N) {
        d = min(degi[n], NBIN - 1);
        lrank = atomicAdd(&lbin[d], 1);
    }
    __syncthreads();
    if (t < NBIN && lbin[t] > 0) lbase[t] = atomicAdd(&bincur[t], lbin[t]);
    __syncthreads();
    if (n < N) {
        int slot = lbase[d] + lrank;
        int base = edgebase[d] + (slot - binstart[d]);
        perm[slot] = n;
        int2 m;
        m.x = base;
        m.y = bins[d] | (d << 20);
        meta[slot] = m;
        int4 im;
        im.x = base;
        im.y = bins[d];
        im.z = __float_as_int(dinv[n]);
        im.w = 0;
        invmeta[n] = im;
    }
}

// ---------------- CSR fill (atomic-free scatter: rank precomputed in deg pass) --------
// Chain: {dst->invmeta} || {erank} || {src->dinv[s]} -> store. Depth 2 (R12).
// record = (fp16(dinv[s]*dinv[d]) << 16) | src   (src < 65536 fits 16 bits)
__global__ __launch_bounds__(256) void k_fill(const int* __restrict__ src,
                                              const int* __restrict__ dst,
                                              const float* __restrict__ dinv,
                                              const int4* __restrict__ invmeta,
                                              const int* __restrict__ erank,
                                              unsigned int* __restrict__ edata) {
    int e = blockIdx.x * 256 + threadIdx.x;
    if (e >= N_EDGES) return;
    int s = src[e], d = dst[e];
    int4 im = invmeta[d];               // base | stride | dinv[d]
    int j = erank[e];
    float wdd = __int_as_float(im.z);
    float wss = dinv[s];
    int pos = im.x + j * im.y;
    _Float16 hw = (_Float16)(wss * wdd);     // RTN
    edata[pos] = ((unsigned int)__builtin_bit_cast(unsigned short, hw) << 16) |
                 (unsigned int)s;
}

// ---------------- MFMA fp16 GEMM: W-resident-in-LDS, streaming A, 512 threads ------
// R15 got ~33us/layer but static 64KB LDS capped residency at 2 blocks/CU = 8
// waves/CU (2/SIMD) — thin latency hiding for the global-A + ds_read k-loop.
// R16: 512-thread blocks (8 waves, one 16-row strip each, no strip loop) -> 16
// waves/CU; DYNAMIC LDS sized to K (K=128 layer: 32KB -> more blocks/CU).
// Read/write swizzle, k-order, accumulation order unchanged -> bit-identical.
__global__ __launch_bounds__(512) void k_gemm(const _Float16* __restrict__ A,
                                              const _Float16* __restrict__ Wh,
                                              const float* __restrict__ bnscale,
                                              const float* __restrict__ bnshift,
                                              _Float16* __restrict__ X16, int K) {
    extern __shared__ _Float16 sw[];      // 128 * K fp16 (64KB @ K=256)
    int tid = threadIdx.x;
    int lane = tid & 63;
    int w = tid >> 6;                     // 0..7, one 16-row strip per wave
    int segs = K >> 3;                    // 32 (K=256) or 16 (K=128)
    int sshift = (K == 256) ? 5 : 4;
    int col0 = blockIdx.y * 128;

    // one-time W stage: seg s of col swizzled to s^(col&7)
    int cnt = (128 * segs) >> 9;          // segs per thread (8 or 4)
    for (int i = 0; i < cnt; ++i) {
        int g = tid * cnt + i;
        int col = g >> sshift;
        int s = g & (segs - 1);
        f16x8 v = *(const f16x8*)(Wh + (size_t)(col0 + col) * K + s * 8);
        *(f16x8*)(sw + ((size_t)col << (sshift + 3)) + ((s ^ (col & 7)) << 3)) = v;
    }
    __syncthreads();

    int m = lane & 15, q = lane >> 4;
    int row0 = blockIdx.x * 128 + w * 16;

    f32x4 acc[8] = {};
    const _Float16* Abase = A + (size_t)(row0 + m) * K + q * 8;
    for (int k0 = 0; k0 < K; k0 += 32) {
        f16x8 af = *(const f16x8*)(Abase + k0);
        int sbase = (k0 >> 3) + q;
        #pragma unroll
        for (int c = 0; c < 8; ++c) {
            int col = c * 16 + m;
            f16x8 whf = *(const f16x8*)(sw + (col << (sshift + 3)) +
                                        ((sbase ^ (col & 7)) << 3));
            acc[c] = __builtin_amdgcn_mfma_f32_16x16x32_f16(af, whf, acc[c], 0, 0, 0);
        }
    }
    int mrow = row0 + q * 4;
    #pragma unroll
    for (int c = 0; c < 8; ++c) {
        int n = col0 + c * 16 + m;
        float sc = bnscale[n];
        float sh = bnshift[n];
        f32x4 v = acc[c];
        _Float16* base = X16 + (size_t)(n >> 5) * (N_NODES * 32) + (n & 31);
        #pragma unroll
        for (int g = 0; g < 4; ++g)
            if (mrow + g < N_NODES)
                base[(size_t)(mrow + g) * 32] =
                    (_Float16)fmaxf(fmaf(v[g], sc, sh), 0.f);
    }
}

// ---------------- chunked gather on fp16 X: Âx -> fp16 A node-major ----------------
// R7 form (proven best). ONE chunk/block (R8: 2 chunks blew per-XCD L2). One slot
// per quad (R9: pairing wasted issue). 8-deep unroll; packed 4B records; edata
// loads PLAIN (R1); longest-first nb order (R4/R5 win).
#define GNB 782  // ceil(50000/64) slot-blocks per chunk

__global__ __launch_bounds__(256) void k_gather(const _Float16* __restrict__ Xc,
                                                const int2* __restrict__ meta,
                                                const unsigned int* __restrict__ edata,
                                                const int* __restrict__ perm,
                                                const float* __restrict__ selfn,
                                                _Float16* __restrict__ A,
                                                int K, int cshift) {
    int bid = blockIdx.x;
    int chunk = bid & ((1 << cshift) - 1);
    int nb = (GNB - 1) - (bid >> cshift);   // longest-work-first
    const _Float16* Hc = Xc + (size_t)chunk * (N_NODES * 32);
    int slot = nb * 64 + (threadIdx.x >> 2);
    if (slot >= N_NODES) return;
    int node = perm[slot];
    int2 m = meta[slot];
    int q8 = (threadIdx.x & 3) * 8;

    int stride = m.y & 0xFFFFF;
    int deg = m.y >> 20;
    const unsigned int* ep = edata + m.x;
    float sn = selfn[node];

    float acc[8];
    {
        f16x8 hv = *(const f16x8*)(Hc + (size_t)node * 32 + q8);
        #pragma unroll
        for (int i = 0; i < 8; ++i) acc[i] = (float)hv[i] * sn;
    }

    int j = 0;
    for (; j + 7 < deg; j += 8) {
        unsigned int e[8];
        #pragma unroll
        for (int i = 0; i < 8; ++i)
            e[i] = ep[(size_t)(j + i) * stride];
        f16x8 a[8];
        #pragma unroll
        for (int i = 0; i < 8; ++i)
            a[i] = *(const f16x8*)(Hc + (size_t)(e[i] & 0xFFFFu) * 32 + q8);
        #pragma unroll
        for (int i = 0; i < 8; ++i) {
            float w = (float)__builtin_bit_cast(_Float16, (unsigned short)(e[i] >> 16));
            #pragma unroll
            for (int c = 0; c < 8; ++c) acc[c] = fmaf((float)a[i][c], w, acc[c]);
        }
    }
    if (j + 3 < deg) {
        unsigned int e[4];
        #pragma unroll
        for (int i = 0; i < 4; ++i)
            e[i] = ep[(size_t)(j + i) * stride];
        f16x8 a[4];
        #pragma unroll
        for (int i = 0; i < 4; ++i)
            a[i] = *(const f16x8*)(Hc + (size_t)(e[i] & 0xFFFFu) * 32 + q8);
        #pragma unroll
        for (int i = 0; i < 4; ++i) {
            float w = (float)__builtin_bit_cast(_Float16, (unsigned short)(e[i] >> 16));
            #pragma unroll
            for (int c = 0; c < 8; ++c) acc[c] = fmaf((float)a[i][c], w, acc[c]);
        }
        j += 4;
    }
    for (; j < deg; ++j) {
        unsigned int e0 = ep[(size_t)j * stride];
        f16x8 a0 = *(const f16x8*)(Hc + (size_t)(e0 & 0xFFFFu) * 32 + q8);
        float w0 = (float)__builtin_bit_cast(_Float16, (unsigned short)(e0 >> 16));
        #pragma unroll
        for (int i = 0; i < 8; ++i) acc[i] = fmaf((float)a0[i], w0, acc[i]);
    }

    f16x8 o;
    #pragma unroll
    for (int i = 0; i < 8; ++i) o[i] = (_Float16)acc[i];
    u32x4 uv = *(u32x4*)&o;
    __builtin_nontemporal_store(uv, (u32x4*)(A + (size_t)node * K + chunk * 32 + q8));
}

// ---------------- fused mean-pool + MLP head (one block per graph) ----------------
// R12: 4-way node unroll — independent accumulator chains instead of 1 serial walk.
__global__ __launch_bounds__(128) void k_poolmlp(const _Float16* __restrict__ X16,
                                                 const int* __restrict__ gstart,
                                                 const int* __restrict__ gend,
                                                 const float* __restrict__ W1,
                                                 const float* __restrict__ b1,
                                                 const float* __restrict__ W2,
                                                 const float* __restrict__ b2,
                                                 float* __restrict__ out) {
    __shared__ float prow[HID];
    __shared__ float hred[2];
    int g = blockIdx.x;
    int s = gstart[g], e = gend[g];
    int j = threadIdx.x; // 0..127, channels j and j+128
    const _Float16* p0 = X16 + (size_t)(j >> 5) * (N_NODES * 32) + (j & 31);
    const _Float16* p1 = X16 + (size_t)((j >> 5) + 4) * (N_NODES * 32) + (j & 31);
    float a0 = 0.f, a1 = 0.f, b0 = 0.f, b1v = 0.f, c0 = 0.f, c1 = 0.f, d0 = 0.f, d1 = 0.f;
    int n = s;
    for (; n + 3 < e; n += 4) {
        a0 += (float)p0[(size_t)n * 32];
        a1 += (float)p1[(size_t)n * 32];
        b0 += (float)p0[(size_t)(n + 1) * 32];
        b1v += (float)p1[(size_t)(n + 1) * 32];
        c0 += (float)p0[(size_t)(n + 2) * 32];
        c1 += (float)p1[(size_t)(n + 2) * 32];
        d0 += (float)p0[(size_t)(n + 3) * 32];
        d1 += (float)p1[(size_t)(n + 3) * 32];
    }
    for (; n < e; ++n) {
        a0 += (float)p0[(size_t)n * 32];
        a1 += (float)p1[(size_t)n * 32];
    }
    a0 = (a0 + b0) + (c0 + d0);
    a1 = (a1 + b1v) + (c1 + d1);
    float inv = 1.0f / fmaxf((float)(e - s), 1.0f);
    prow[j] = a0 * inv;
    prow[j + 128] = a1 * inv;
    __syncthreads();
    float acc = 0.f;
    #pragma unroll 8
    for (int k = 0; k < HID; ++k) acc += prow[k] * W1[k * 128 + j];
    float h = fmaxf(acc + b1[j], 0.f);
    float p = h * W2[j];
    #pragma unroll
    for (int off = 32; off > 0; off >>= 1) p += __shfl_down(p, off, 64);
    if ((j & 63) == 0) hred[j >> 6] = p;
    __syncthreads();
    if (j == 0) out[g] = hred[0] + hred[1] + b2[0];
}

extern "C" void kernel_launch(void* const* d_in, const int* in_sizes, int n_in,
                              void* d_out, int out_size, void* d_ws, size_t ws_size,
                              hipStream_t stream) {
    const float* x      = (const float*)d_in[0];
    const int*   ei     = (const int*)d_in[1];
    const int*   batch  = (const int*)d_in[2];
    const float* convW0 = (const float*)d_in[3];
    const float* convWs = (const float*)d_in[4];
    const float* convB  = (const float*)d_in[5];
    const float* gamma  = (const float*)d_in[6];
    const float* beta   = (const float*)d_in[7];
    const float* mean   = (const float*)d_in[8];
    const float* var    = (const float*)d_in[9];
    const float* lin1W  = (const float*)d_in[10];
    const float* lin1b  = (const float*)d_in[11];
    const float* lin2W  = (const float*)d_in[12];
    const float* lin2b  = (const float*)d_in[13];
    float* out = (float*)d_out;

    const int* src = ei;
    const int* dst = ei + N_EDGES;

    const int WTOT = 128 * 256 + 3 * 256 * 256; // 229376

    char* wsb = (char*)d_ws;
    _Float16* x16a = (_Float16*)wsb;                     // N*HID fp16 (ping)
    _Float16* x16b = x16a + (size_t)N_NODES * HID;       // N*HID fp16 (pong)
    _Float16* Ab   = x16b + (size_t)N_NODES * HID;       // N*HID fp16 (GEMM A operand)
    _Float16* Wh16 = Ab + (size_t)N_NODES * HID;         // WTOT fp16
    _Float16* Wl16 = Wh16 + WTOT;                        // WTOT fp16 (unused, kept for layout)
    float* dinv    = (float*)(Wl16 + WTOT);              // N
    float* selfn   = dinv + N_NODES;                     // N
    float* bnscale = selfn + N_NODES;                    // 4*HID
    float* bnshift = bnscale + N_LAYERS * HID;           // 4*HID
    // contiguous zero-init region: degi | bins | gstart | gend
    int*   degi    = (int*)(bnshift + N_LAYERS * HID);   // N
    int*   bins    = degi + N_NODES;                     // NBIN
    int*   gstart  = bins + NBIN;                        // G
    int*   gend    = gstart + N_GRAPHS;                  // G
    int*   binstart= gend + N_GRAPHS;                    // NBIN
    int*   bincur  = binstart + NBIN;                    // NBIN
    int*   edgebase= bincur + NBIN;                      // NBIN
    int*   perm    = edgebase + NBIN;                    // N
    int2*  meta    = (int2*)(perm + N_NODES);            // N int2
    int4*  invmeta = (int4*)(meta + N_NODES);            // N int4 (per-node fill meta)
    int*   erank   = (int*)(invmeta + N_NODES);          // E (edge rank within dst)
    unsigned int* edata = (unsigned int*)(erank + N_EDGES); // E u32 (packed)

    hipMemsetAsync(degi, 0, (size_t)(N_NODES + NBIN + 2 * N_GRAPHS) * 4, stream);

    // CSR build + norms + degree sort; prep fused under degbounds (R11); erank (R12)
    const int PREP_TOT = N_LAYERS * HID + WTOT + N_NODES * IN_DIM / 4;
    const int PREP_BLKS = (PREP_TOT + 255) / 256;
    k_degboundsprep<<<EDGE_BLKS + NODE_BLKS + PREP_BLKS, 256, 0, stream>>>(
        dst, degi, erank, batch, gstart, gend,
        gamma, beta, mean, var, convB, convW0, convWs, x,
        bnscale, bnshift, Wh16, x16a);
    k_nodeprep<<<NODE_BLKS, 256, 0, stream>>>(degi, dinv, selfn, bins, N_NODES);
    k_binscan<<<1, 64, 0, stream>>>(bins, binstart, bincur, edgebase);
    k_assign<<<NODE_BLKS, 256, 0, stream>>>(degi, binstart, edgebase, bins, bincur, dinv,
                                            perm, invmeta, meta, N_NODES);

    // CSR fill (atomic-free scatter)
    k_fill<<<EDGE_BLKS, 256, 0, stream>>>(src, dst, dinv, invmeta, erank, edata);

    // layers: gather (Âx, fp16) -> W-in-LDS streaming GEMM, 512 thr (+BN+ReLU)
    dim3 gg((N_NODES + 127) / 128, 2);
    _Float16* cur = x16a;
    for (int l = 0; l < N_LAYERS; ++l) {
        int K = (l == 0) ? IN_DIM : HID;
        int nchunk = K / 32;
        int cshift = (l == 0) ? 2 : 3;
        size_t woff = (l == 0) ? 0 : (size_t)(32768 + (l - 1) * 65536);
        size_t ldsb = (size_t)128 * K * sizeof(_Float16);
        k_gather<<<nchunk * GNB, 256, 0, stream>>>(cur, meta, edata, perm, selfn,
                                                   Ab, K, cshift);
        _Float16* nxt = (cur == x16a) ? x16b : x16a;
        k_gemm<<<gg, 512, ldsb, stream>>>(Ab, Wh16 + woff,
                                          bnscale + l * HID, bnshift + l * HID, nxt, K);
        cur = nxt;
    }

    k_poolmlp<<<N_GRAPHS, 128, 0, stream>>>(cur, gstart, gend, lin1W, lin1b, lin2W, lin2b, out);
}

// Round 17
// 422.843 us; speedup vs baseline: 1.2937x; 1.0250x over previous
//
#include <hip/hip_runtime.h>

#define N_NODES 50000
#define N_EDGES 800000
#define N_GRAPHS 2048
#define IN_DIM 128
#define HID 256
#define N_LAYERS 4
#define BN_EPS 1e-5f
#define NBIN 128
#define WSCALE 64.0f

#define EDGE_BLKS 3125   // ceil(800000/256)
#define NODE_BLKS 196    // ceil(50000/256)

typedef unsigned short ushort_t;
typedef float f32x4 __attribute__((ext_vector_type(4)));
typedef unsigned int u32x4 __attribute__((ext_vector_type(4)));
typedef _Float16 f16x8 __attribute__((ext_vector_type(8)));
typedef _Float16 f16x4 __attribute__((ext_vector_type(4)));

// ---------------- deg count (+edge rank) + graph bounds + prep (fused grid) ----------
// R12: the deg atomic's return value IS each edge's rank within its dst group —
// store it (erank) so k_fill needs no cursor atomic at all (chain depth 3 -> 2).
__global__ __launch_bounds__(256) void k_degboundsprep(const int* __restrict__ dst,
                                                       int* __restrict__ degi,
                                                       int* __restrict__ erank,
                                                       const int* __restrict__ batch,
                                                       int* __restrict__ gstart,
                                                       int* __restrict__ gend,
                                                       const float* __restrict__ gamma,
                                                       const float* __restrict__ beta,
                                                       const float* __restrict__ mean,
                                                       const float* __restrict__ var,
                                                       const float* __restrict__ bias,
                                                       const float* __restrict__ W0,
                                                       const float* __restrict__ Ws,
                                                       const float* __restrict__ x,
                                                       float* __restrict__ scale,
                                                       float* __restrict__ shift,
                                                       _Float16* __restrict__ Wh,
                                                       _Float16* __restrict__ X16) {
    int bid = blockIdx.x;
    if (bid < EDGE_BLKS) {
        int e = bid * 256 + threadIdx.x;
        if (e < N_EDGES) erank[e] = atomicAdd(&degi[dst[e]], 1);
        return;
    }
    if (bid < EDGE_BLKS + NODE_BLKS) {
        int n = (bid - EDGE_BLKS) * 256 + threadIdx.x;
        if (n >= N_NODES) return;
        int g = batch[n];
        if (n == 0 || batch[n - 1] != g) gstart[g] = n;
        if (n == N_NODES - 1 || batch[n + 1] != g) gend[g] = n + 1;
        return;
    }
    int id = (bid - EDGE_BLKS - NODE_BLKS) * 256 + threadIdx.x;
    if (id < N_LAYERS * HID) {
        float s = gamma[id] * rsqrtf(var[id] + BN_EPS);
        scale[id] = s / WSCALE;
        shift[id] = beta[id] + (bias[id] - mean[id]) * s;
        return;
    }
    id -= N_LAYERS * HID;
    const int WT = 128 * 256 + 3 * 256 * 256;
    if (id < WT) {
        float v;
        if (id < 32768) {
            int n = id >> 7, k = id & 127;
            v = W0[k * 256 + n];
        } else {
            int t = id - 32768;
            int l = t >> 16;
            int r = t & 65535;
            int n = r >> 8, k = r & 255;
            v = Ws[l * 65536 + k * 256 + n];
        }
        Wh[id] = (_Float16)(v * WSCALE);
        return;
    }
    id -= WT;
    const int total4 = N_NODES * IN_DIM / 4;
    if (id < total4) {
        float4 v = ((const float4*)x)[id];
        int n = id >> 5;
        int c0 = (id & 31) * 4;
        f16x4 o;
        o.x = (_Float16)v.x; o.y = (_Float16)v.y; o.z = (_Float16)v.z; o.w = (_Float16)v.w;
        *(f16x4*)(X16 + (size_t)(c0 >> 5) * (N_NODES * 32) + (size_t)n * 32 + (c0 & 31)) = o;
    }
}

// ---------------- node norms + degree histogram (fused, hierarchical) ----------------
__global__ __launch_bounds__(256) void k_nodeprep(const int* __restrict__ degi,
                                                  float* __restrict__ dinv,
                                                  float* __restrict__ selfn,
                                                  int* __restrict__ bins, int N) {
    __shared__ int lbin[NBIN];
    int t = threadIdx.x;
    if (t < NBIN) lbin[t] = 0;
    __syncthreads();
    int n = blockIdx.x * 256 + t;
    if (n < N) {
        int dg = degi[n];
        float d = 1.0f + (float)dg;
        dinv[n] = 1.0f / sqrtf(d);
        selfn[n] = 1.0f / d;
        atomicAdd(&lbin[min(dg, NBIN - 1)], 1);
    }
    __syncthreads();
    if (t < NBIN && lbin[t] > 0) atomicAdd(&bins[t], lbin[t]);
}

// ---------------- bin prefix (one wave, shfl scan over 128 bins) ----------------
__global__ void k_binscan(const int* __restrict__ bins, int* __restrict__ binstart,
                          int* __restrict__ bincur, int* __restrict__ edgebase) {
    int t = threadIdx.x & 63;
    int d0 = 2 * t, d1 = 2 * t + 1;
    int a = bins[d0], b = bins[d1];
    int ea = a * d0, eb = b * d1;
    int s = a + b, es = ea + eb;
    int ps = s, pe = es;
    #pragma unroll
    for (int off = 1; off < 64; off <<= 1) {
        int u = __shfl_up(ps, off, 64);
        int v = __shfl_up(pe, off, 64);
        if (t >= off) { ps += u; pe += v; }
    }
    int exs = ps - s, exe = pe - es;
    binstart[d0] = exs;     bincur[d0] = exs;     edgebase[d0] = exe;
    binstart[d1] = exs + a; bincur[d1] = exs + a; edgebase[d1] = exe + ea;
}

// ---------------- parallel slot assignment; emits per-slot meta + per-NODE fill meta ----------
// invmeta[n] = {edata_base, stride, bits(dinv[n]), 0} (R7 win).
__global__ __launch_bounds__(256) void k_assign(const int* __restrict__ degi,
                                                const int* __restrict__ binstart,
                                                const int* __restrict__ edgebase,
                                                const int* __restrict__ bins,
                                                int* __restrict__ bincur,
                                                const float* __restrict__ dinv,
                                                int* __restrict__ perm,
                                                int4* __restrict__ invmeta,
                                                int2* __restrict__ meta,
                                                int N) {
    __shared__ int lbin[NBIN];
    __shared__ int lbase[NBIN];
    int t = threadIdx.x;
    if (t < NBIN) lbin[t] = 0;
    __syncthreads();
    int n = blockIdx.x * 256 + t;
    int d = 0, lrank = 0;
    if (n < N) {
        d = min(degi[n], NBIN - 1);
        lrank = atomicAdd(&lbin[d], 1);
    }
    __syncthreads();
    if (t < NBIN && lbin[t] > 0) lbase[t] = atomicAdd(&bincur[t], lbin[t]);
    __syncthreads();
    if (n < N) {
        int slot = lbase[d] + lrank;
        int base = edgebase[d] + (slot - binstart[d]);
        perm[slot] = n;
        int2 m;
        m.x = base;
        m.y = bins[d] | (d << 20);
        meta[slot] = m;
        int4 im;
        im.x = base;
        im.y = bins[d];
        im.z = __float_as_int(dinv[n]);
        im.w = 0;
        invmeta[n] = im;
    }
}

// ---------------- CSR fill (atomic-free scatter: rank precomputed in deg pass) --------
// Chain: {dst->invmeta} || {erank} || {src->dinv[s]} -> store. Depth 2 (R12).
// record = (fp16(dinv[s]*dinv[d]) << 16) | src   (src < 65536 fits 16 bits)
__global__ __launch_bounds__(256) void k_fill(const int* __restrict__ src,
                                              const int* __restrict__ dst,
                                              const float* __restrict__ dinv,
                                              const int4* __restrict__ invmeta,
                                              const int* __restrict__ erank,
                                              unsigned int* __restrict__ edata) {
    int e = blockIdx.x * 256 + threadIdx.x;
    if (e >= N_EDGES) return;
    int s = src[e], d = dst[e];
    int4 im = invmeta[d];               // base | stride | dinv[d]
    int j = erank[e];
    float wdd = __int_as_float(im.z);
    float wss = dinv[s];
    int pos = im.x + j * im.y;
    _Float16 hw = (_Float16)(wss * wdd);     // RTN
    edata[pos] = ((unsigned int)__builtin_bit_cast(unsigned short, hw) << 16) |
                 (unsigned int)s;
}

// ---------------- MFMA fp16 GEMM: W-resident-in-LDS, streaming A, 512 threads ------
// R16 structure (proven: 33->~27us/layer). R17: explicit A-prefetch — load the
// next k-step's A fragment before the MFMA cluster so the global load overlaps
// MFMA+ds_read even across the runtime-K loop. Bit-identical accumulation.
__global__ __launch_bounds__(512) void k_gemm(const _Float16* __restrict__ A,
                                              const _Float16* __restrict__ Wh,
                                              const float* __restrict__ bnscale,
                                              const float* __restrict__ bnshift,
                                              _Float16* __restrict__ X16, int K) {
    extern __shared__ _Float16 sw[];      // 128 * K fp16 (64KB @ K=256)
    int tid = threadIdx.x;
    int lane = tid & 63;
    int w = tid >> 6;                     // 0..7, one 16-row strip per wave
    int segs = K >> 3;                    // 32 (K=256) or 16 (K=128)
    int sshift = (K == 256) ? 5 : 4;
    int col0 = blockIdx.y * 128;

    // one-time W stage: seg s of col swizzled to s^(col&7)
    int cnt = (128 * segs) >> 9;          // segs per thread (8 or 4)
    for (int i = 0; i < cnt; ++i) {
        int g = tid * cnt + i;
        int col = g >> sshift;
        int s = g & (segs - 1);
        f16x8 v = *(const f16x8*)(Wh + (size_t)(col0 + col) * K + s * 8);
        *(f16x8*)(sw + ((size_t)col << (sshift + 3)) + ((s ^ (col & 7)) << 3)) = v;
    }
    __syncthreads();

    int m = lane & 15, q = lane >> 4;
    int row0 = blockIdx.x * 128 + w * 16;

    f32x4 acc[8] = {};
    const _Float16* Abase = A + (size_t)(row0 + m) * K + q * 8;
    f16x8 af = *(const f16x8*)(Abase);
    for (int k0 = 0; k0 < K; k0 += 32) {
        f16x8 af_next;
        if (k0 + 32 < K) af_next = *(const f16x8*)(Abase + k0 + 32);
        int sbase = (k0 >> 3) + q;
        #pragma unroll
        for (int c = 0; c < 8; ++c) {
            int col = c * 16 + m;
            f16x8 whf = *(const f16x8*)(sw + (col << (sshift + 3)) +
                                        ((sbase ^ (col & 7)) << 3));
            acc[c] = __builtin_amdgcn_mfma_f32_16x16x32_f16(af, whf, acc[c], 0, 0, 0);
        }
        af = af_next;
    }
    int mrow = row0 + q * 4;
    #pragma unroll
    for (int c = 0; c < 8; ++c) {
        int n = col0 + c * 16 + m;
        float sc = bnscale[n];
        float sh = bnshift[n];
        f32x4 v = acc[c];
        _Float16* base = X16 + (size_t)(n >> 5) * (N_NODES * 32) + (n & 31);
        #pragma unroll
        for (int g = 0; g < 4; ++g)
            if (mrow + g < N_NODES)
                base[(size_t)(mrow + g) * 32] =
                    (_Float16)fmaxf(fmaf(v[g], sc, sh), 0.f);
    }
}

// ---------------- chunked gather on fp16 X: Âx -> fp16 A node-major ----------------
// R7 form + R17 16-deep main loop: the heavy (deg>=32) blocks set the makespan
// under longest-first order; 16 in-flight record+feature chains halves their
// latency round-trips. Light blocks use the 8/4/1 tails unchanged.
// ONE chunk/block (R8); one slot/quad (R9); edata PLAIN (R1); longest-first (R4).
#define GNB 782  // ceil(50000/64) slot-blocks per chunk

__global__ __launch_bounds__(256) void k_gather(const _Float16* __restrict__ Xc,
                                                const int2* __restrict__ meta,
                                                const unsigned int* __restrict__ edata,
                                                const int* __restrict__ perm,
                                                const float* __restrict__ selfn,
                                                _Float16* __restrict__ A,
                                                int K, int cshift) {
    int bid = blockIdx.x;
    int chunk = bid & ((1 << cshift) - 1);
    int nb = (GNB - 1) - (bid >> cshift);   // longest-work-first
    const _Float16* Hc = Xc + (size_t)chunk * (N_NODES * 32);
    int slot = nb * 64 + (threadIdx.x >> 2);
    if (slot >= N_NODES) return;
    int node = perm[slot];
    int2 m = meta[slot];
    int q8 = (threadIdx.x & 3) * 8;

    int stride = m.y & 0xFFFFF;
    int deg = m.y >> 20;
    const unsigned int* ep = edata + m.x;
    float sn = selfn[node];

    float acc[8];
    {
        f16x8 hv = *(const f16x8*)(Hc + (size_t)node * 32 + q8);
        #pragma unroll
        for (int i = 0; i < 8; ++i) acc[i] = (float)hv[i] * sn;
    }

    int j = 0;
    for (; j + 15 < deg; j += 16) {
        unsigned int e[16];
        #pragma unroll
        for (int i = 0; i < 16; ++i)
            e[i] = ep[(size_t)(j + i) * stride];
        f16x8 a[16];
        #pragma unroll
        for (int i = 0; i < 16; ++i)
            a[i] = *(const f16x8*)(Hc + (size_t)(e[i] & 0xFFFFu) * 32 + q8);
        #pragma unroll
        for (int i = 0; i < 16; ++i) {
            float w = (float)__builtin_bit_cast(_Float16, (unsigned short)(e[i] >> 16));
            #pragma unroll
            for (int c = 0; c < 8; ++c) acc[c] = fmaf((float)a[i][c], w, acc[c]);
        }
    }
    if (j + 7 < deg) {
        unsigned int e[8];
        #pragma unroll
        for (int i = 0; i < 8; ++i)
            e[i] = ep[(size_t)(j + i) * stride];
        f16x8 a[8];
        #pragma unroll
        for (int i = 0; i < 8; ++i)
            a[i] = *(const f16x8*)(Hc + (size_t)(e[i] & 0xFFFFu) * 32 + q8);
        #pragma unroll
        for (int i = 0; i < 8; ++i) {
            float w = (float)__builtin_bit_cast(_Float16, (unsigned short)(e[i] >> 16));
            #pragma unroll
            for (int c = 0; c < 8; ++c) acc[c] = fmaf((float)a[i][c], w, acc[c]);
        }
        j += 8;
    }
    if (j + 3 < deg) {
        unsigned int e[4];
        #pragma unroll
        for (int i = 0; i < 4; ++i)
            e[i] = ep[(size_t)(j + i) * stride];
        f16x8 a[4];
        #pragma unroll
        for (int i = 0; i < 4; ++i)
            a[i] = *(const f16x8*)(Hc + (size_t)(e[i] & 0xFFFFu) * 32 + q8);
        #pragma unroll
        for (int i = 0; i < 4; ++i) {
            float w = (float)__builtin_bit_cast(_Float16, (unsigned short)(e[i] >> 16));
            #pragma unroll
            for (int c = 0; c < 8; ++c) acc[c] = fmaf((float)a[i][c], w, acc[c]);
        }
        j += 4;
    }
    for (; j < deg; ++j) {
        unsigned int e0 = ep[(size_t)j * stride];
        f16x8 a0 = *(const f16x8*)(Hc + (size_t)(e0 & 0xFFFFu) * 32 + q8);
        float w0 = (float)__builtin_bit_cast(_Float16, (unsigned short)(e0 >> 16));
        #pragma unroll
        for (int i = 0; i < 8; ++i) acc[i] = fmaf((float)a0[i], w0, acc[i]);
    }

    f16x8 o;
    #pragma unroll
    for (int i = 0; i < 8; ++i) o[i] = (_Float16)acc[i];
    u32x4 uv = *(u32x4*)&o;
    __builtin_nontemporal_store(uv, (u32x4*)(A + (size_t)node * K + chunk * 32 + q8));
}

// ---------------- fused mean-pool + MLP head (one block per graph) ----------------
// R12: 4-way node unroll — independent accumulator chains instead of 1 serial walk.
__global__ __launch_bounds__(128) void k_poolmlp(const _Float16* __restrict__ X16,
                                                 const int* __restrict__ gstart,
                                                 const int* __restrict__ gend,
                                                 const float* __restrict__ W1,
                                                 const float* __restrict__ b1,
                                                 const float* __restrict__ W2,
                                                 const float* __restrict__ b2,
                                                 float* __restrict__ out) {
    __shared__ float prow[HID];
    __shared__ float hred[2];
    int g = blockIdx.x;
    int s = gstart[g], e = gend[g];
    int j = threadIdx.x; // 0..127, channels j and j+128
    const _Float16* p0 = X16 + (size_t)(j >> 5) * (N_NODES * 32) + (j & 31);
    const _Float16* p1 = X16 + (size_t)((j >> 5) + 4) * (N_NODES * 32) + (j & 31);
    float a0 = 0.f, a1 = 0.f, b0 = 0.f, b1v = 0.f, c0 = 0.f, c1 = 0.f, d0 = 0.f, d1 = 0.f;
    int n = s;
    for (; n + 3 < e; n += 4) {
        a0 += (float)p0[(size_t)n * 32];
        a1 += (float)p1[(size_t)n * 32];
        b0 += (float)p0[(size_t)(n + 1) * 32];
        b1v += (float)p1[(size_t)(n + 1) * 32];
        c0 += (float)p0[(size_t)(n + 2) * 32];
        c1 += (float)p1[(size_t)(n + 2) * 32];
        d0 += (float)p0[(size_t)(n + 3) * 32];
        d1 += (float)p1[(size_t)(n + 3) * 32];
    }
    for (; n < e; ++n) {
        a0 += (float)p0[(size_t)n * 32];
        a1 += (float)p1[(size_t)n * 32];
    }
    a0 = (a0 + b0) + (c0 + d0);
    a1 = (a1 + b1v) + (c1 + d1);
    float inv = 1.0f / fmaxf((float)(e - s), 1.0f);
    prow[j] = a0 * inv;
    prow[j + 128] = a1 * inv;
    __syncthreads();
    float acc = 0.f;
    #pragma unroll 8
    for (int k = 0; k < HID; ++k) acc += prow[k] * W1[k * 128 + j];
    float h = fmaxf(acc + b1[j], 0.f);
    float p = h * W2[j];
    #pragma unroll
    for (int off = 32; off > 0; off >>= 1) p += __shfl_down(p, off, 64);
    if ((j & 63) == 0) hred[j >> 6] = p;
    __syncthreads();
    if (j == 0) out[g] = hred[0] + hred[1] + b2[0];
}

extern "C" void kernel_launch(void* const* d_in, const int* in_sizes, int n_in,
                              void* d_out, int out_size, void* d_ws, size_t ws_size,
                              hipStream_t stream) {
    const float* x      = (const float*)d_in[0];
    const int*   ei     = (const int*)d_in[1];
    const int*   batch  = (const int*)d_in[2];
    const float* convW0 = (const float*)d_in[3];
    const float* convWs = (const float*)d_in[4];
    const float* convB  = (const float*)d_in[5];
    const float* gamma  = (const float*)d_in[6];
    const float* beta   = (const float*)d_in[7];
    const float* mean   = (const float*)d_in[8];
    const float* var    = (const float*)d_in[9];
    const float* lin1W  = (const float*)d_in[10];
    const float* lin1b  = (const float*)d_in[11];
    const float* lin2W  = (const float*)d_in[12];
    const float* lin2b  = (const float*)d_in[13];
    float* out = (float*)d_out;

    const int* src = ei;
    const int* dst = ei + N_EDGES;

    const int WTOT = 128 * 256 + 3 * 256 * 256; // 229376

    char* wsb = (char*)d_ws;
    _Float16* x16a = (_Float16*)wsb;                     // N*HID fp16 (ping)
    _Float16* x16b = x16a + (size_t)N_NODES * HID;       // N*HID fp16 (pong)
    _Float16* Ab   = x16b + (size_t)N_NODES * HID;       // N*HID fp16 (GEMM A operand)
    _Float16* Wh16 = Ab + (size_t)N_NODES * HID;         // WTOT fp16
    _Float16* Wl16 = Wh16 + WTOT;                        // WTOT fp16 (unused, kept for layout)
    float* dinv    = (float*)(Wl16 + WTOT);              // N
    float* selfn   = dinv + N_NODES;                     // N
    float* bnscale = selfn + N_NODES;                    // 4*HID
    float* bnshift = bnscale + N_LAYERS * HID;           // 4*HID
    // contiguous zero-init region: degi | bins | gstart | gend
    int*   degi    = (int*)(bnshift + N_LAYERS * HID);   // N
    int*   bins    = degi + N_NODES;                     // NBIN
    int*   gstart  = bins + NBIN;                        // G
    int*   gend    = gstart + N_GRAPHS;                  // G
    int*   binstart= gend + N_GRAPHS;                    // NBIN
    int*   bincur  = binstart + NBIN;                    // NBIN
    int*   edgebase= bincur + NBIN;                      // NBIN
    int*   perm    = edgebase + NBIN;                    // N
    int2*  meta    = (int2*)(perm + N_NODES);            // N int2
    int4*  invmeta = (int4*)(meta + N_NODES);            // N int4 (per-node fill meta)
    int*   erank   = (int*)(invmeta + N_NODES);          // E (edge rank within dst)
    unsigned int* edata = (unsigned int*)(erank + N_EDGES); // E u32 (packed)

    hipMemsetAsync(degi, 0, (size_t)(N_NODES + NBIN + 2 * N_GRAPHS) * 4, stream);

    // CSR build + norms + degree sort; prep fused under degbounds (R11); erank (R12)
    const int PREP_TOT = N_LAYERS * HID + WTOT + N_NODES * IN_DIM / 4;
    const int PREP_BLKS = (PREP_TOT + 255) / 256;
    k_degboundsprep<<<EDGE_BLKS + NODE_BLKS + PREP_BLKS, 256, 0, stream>>>(
        dst, degi, erank, batch, gstart, gend,
        gamma, beta, mean, var, convB, convW0, convWs, x,
        bnscale, bnshift, Wh16, x16a);
    k_nodeprep<<<NODE_BLKS, 256, 0, stream>>>(degi, dinv, selfn, bins, N_NODES);
    k_binscan<<<1, 64, 0, stream>>>(bins, binstart, bincur, edgebase);
    k_assign<<<NODE_BLKS, 256, 0, stream>>>(degi, binstart, edgebase, bins, bincur, dinv,
                                            perm, invmeta, meta, N_NODES);

    // CSR fill (atomic-free scatter)
    k_fill<<<EDGE_BLKS, 256, 0, stream>>>(src, dst, dinv, invmeta, erank, edata);

    // layers: gather (Âx, fp16, 16-deep) -> W-in-LDS streaming GEMM, 512 thr
    dim3 gg((N_NODES + 127) / 128, 2);
    _Float16* cur = x16a;
    for (int l = 0; l < N_LAYERS; ++l) {
        int K = (l == 0) ? IN_DIM : HID;
        int nchunk = K / 32;
        int cshift = (l == 0) ? 2 : 3;
        size_t woff = (l == 0) ? 0 : (size_t)(32768 + (l - 1) * 65536);
        size_t ldsb = (size_t)128 * K * sizeof(_Float16);
        k_gather<<<nchunk * GNB, 256, 0, stream>>>(cur, meta, edata, perm, selfn,
                                                   Ab, K, cshift);
        _Float16* nxt = (cur == x16a) ? x16b : x16a;
        k_gemm<<<gg, 512, ldsb, stream>>>(Ab, Wh16 + woff,
                                          bnscale + l * HID, bnshift + l * HID, nxt, K);
        cur = nxt;
    }

    k_poolmlp<<<N_GRAPHS, 128, 0, stream>>>(cur, gstart, gend, lin1W, lin1b, lin2W, lin2b, out);
}